// Round 2
// baseline (1872.925 us; speedup 1.0000x reference)
//
#include <hip/hip_runtime.h>
#include <hip/hip_bf16.h>

// ---------------------------------------------------------------------------
// Swin shifted-window attention, fully fused per-window kernel.
//   x:[8,128,128,256] f32, w_qkv:[256,768], pos:[15,15], w_out:[256,256], b_out:[256]
//   out:[8,128,128,256] f32
// One block = one (batch, wy, wx) window; 512 threads = 8 waves = 8 heads.
// All matmuls via v_mfma_f32_32x32x16_bf16, fp32 accumulate.
//
// R2 changes vs R1 (which passed at 231 us, occupancy-bound):
//   - ldsX/ldsO unioned -> 32 KB LDS/block (was 64): 2 -> 3 blocks/CU
//   - phase 3 computes O^T directly (A=V^T via makefrag(vv), B=P^T via
//     makefrag(s)) so the LDS spill is 8x ds_write_b64 conflict-free
//     (was 32x scalar ds_write_b16 with 8-way conflicts)
//   - __launch_bounds__(512,6) documents the 3-block/CU VGPR budget (<=85)
//
// MFMA 32x32x16 layouts (guide §3, m74/m101 verified):
//   A-frag: lane l supplies A[m = l%32][k = 8*(l>>5)+i], i=0..7 (8 bf16 = 16B)
//   B-frag: lane l supplies B[k = 8*(l>>5)+i][n = l%32]
//   C/D   : element (row,col): col = l&31, row = (reg&3) + 8*(reg>>2) + 4*(l>>5)
// ---------------------------------------------------------------------------

typedef __attribute__((ext_vector_type(8)))  short bf16x8;
typedef __attribute__((ext_vector_type(16))) float f32x16;

#define MFMA32(a, b, c) __builtin_amdgcn_mfma_f32_32x32x16_bf16((a), (b), (c), 0, 0, 0)

#define QK_SCALE 0.17677669529663687f  // 1/sqrt(32)
#define LOG2E    1.44269504088896340f

__device__ __forceinline__ uint32_t pack2(float lo, float hi) {
  uint32_t l = (uint32_t)__bfloat16_as_ushort(__float2bfloat16(lo));
  uint32_t h = (uint32_t)__bfloat16_as_ushort(__float2bfloat16(hi));
  return l | (h << 16);
}

__device__ __forceinline__ bf16x8 frag_from_u4(uint32_t a, uint32_t b,
                                               uint32_t c, uint32_t d) {
  union { uint32_t u[4]; bf16x8 v; } r;
  r.u[0] = a; r.u[1] = b; r.u[2] = c; r.u[3] = d;
  return r.v;
}

// Assemble an MFMA A/B fragment whose k-dim walks the ROW index of a 32x32
// accumulator M (acc element: row=(reg&3)+8*(reg>>2)+4*hf, col=lane&31) and
// whose m/n index equals col (= lane&31).  Fragment k = 16*kt + 8*hf + i.
// Own lane holds rows with bit2(row)==hf; partner (lane^32, same col) holds
// the complement -> 4 packs + 4 shfl_xor(32) + 4 selects.
__device__ __forceinline__ bf16x8 makefrag(const f32x16& a, int kt, int hf) {
  const int b0 = kt * 8;
  uint32_t q0 = pack2(a[b0 + 0], a[b0 + 1]);
  uint32_t q1 = pack2(a[b0 + 2], a[b0 + 3]);
  uint32_t q2 = pack2(a[b0 + 4], a[b0 + 5]);
  uint32_t q3 = pack2(a[b0 + 6], a[b0 + 7]);
  uint32_t x0 = (uint32_t)__shfl_xor((int)q0, 32, 64);
  uint32_t x1 = (uint32_t)__shfl_xor((int)q1, 32, 64);
  uint32_t x2 = (uint32_t)__shfl_xor((int)q2, 32, 64);
  uint32_t x3 = (uint32_t)__shfl_xor((int)q3, 32, 64);
  uint32_t d0 = hf ? x2 : q0;
  uint32_t d1 = hf ? x3 : q1;
  uint32_t d2 = hf ? q2 : x0;
  uint32_t d3 = hf ? q3 : x1;
  return frag_from_u4(d0, d1, d2, d3);
}

// ---------------------------------------------------------------------------
// Prep: w_qkv [256][768] -> WT bf16 [768][256] (row n = output col, contig k),
//       q-section (n<256) pre-scaled by 1/sqrt(hd);
//       w_out [256][256] -> WoT bf16 [256][256] transposed.
// ---------------------------------------------------------------------------
__global__ void prep_weights(const float* __restrict__ wqkv,
                             const float* __restrict__ wout,
                             ushort* __restrict__ WT,
                             ushort* __restrict__ WoT) {
  int id = blockIdx.x * 256 + threadIdx.x;
  if (id < 196608) {                       // 768*256
    int n = id >> 8, k = id & 255;
    float v = wqkv[k * 768 + n];
    if (n < 256) v *= QK_SCALE;            // fold QK scale into Wq
    WT[id] = __bfloat16_as_ushort(__float2bfloat16(v));
  } else if (id < 262144) {                // + 256*256
    int j = id - 196608;
    int n = j >> 8, k = j & 255;
    WoT[j] = __bfloat16_as_ushort(__float2bfloat16(wout[k * 256 + n]));
  }
}

// ---------------------------------------------------------------------------
__global__ __launch_bounds__(512, 6) void swin_attn(
    const float* __restrict__ x, const float* __restrict__ pos,
    const float* __restrict__ bout, const ushort* __restrict__ WT,
    const ushort* __restrict__ WoT, float* __restrict__ out) {
  // 32 KB union buffer:
  //  phase 0-1: x window bf16, k-grouped: slot(kg,tok) = 16B holding
  //             k=8kg..8kg+7 for token tok; swizzled slot ^= (kg>>2).
  //  phase 3-4: O^T bf16, same k-grouped slot layout (k = h*32+d), no swizzle.
  __shared__ uint4 lds[32 * 64];
  uint4*  ldsX = lds;
  ushort* ldsO = (ushort*)lds;

  const int bid = blockIdx.x;
  const int b  = bid >> 8;
  const int wy = (bid >> 4) & 15;
  const int wx = bid & 15;
  const int t    = threadIdx.x;
  const int lane = t & 63;
  const int h    = t >> 6;                 // wave id == head id
  const int l31  = lane & 31;
  const int hf   = lane >> 5;

  f32x16 zf;
  #pragma unroll
  for (int i = 0; i < 16; ++i) zf[i] = 0.0f;

  // ---- stage shifted x window -> LDS bf16 -------------------------------
  {
    int tok = t >> 3, kc = t & 7;
    int ty = tok >> 3, tx = tok & 7;
    int yy = (wy * 8 + ty + 4) & 127;      // roll(-4,-4) folded into read
    int xx = (wx * 8 + tx + 4) & 127;
    const float* xr = x + (((b * 128 + yy) * 128 + xx) << 8) + kc * 32;
    #pragma unroll
    for (int g = 0; g < 4; ++g) {
      float4 a = *(const float4*)(xr + g * 8);
      float4 c = *(const float4*)(xr + g * 8 + 4);
      uint4 w;
      w.x = pack2(a.x, a.y); w.y = pack2(a.z, a.w);
      w.z = pack2(c.x, c.y); w.w = pack2(c.z, c.w);
      int kg = kc * 4 + g;
      ldsX[(kg * 64 + tok) ^ kc] = w;      // kc == kg>>2
    }
  }
  __syncthreads();

  // ---- phase 1: QKV.  qt/kv accs hold Q^T,K^T (row=d, col=token);
  //      vv holds V (row=token, col=d). Same x-frag feeds all three.
  const ushort* wq = WT + (h * 32 + l31) * 256;
  const ushort* wk = wq + 65536;
  const ushort* wv = wk + 65536;
  f32x16 qt[2], kv[2], vv[2];
  qt[0] = zf; qt[1] = zf; kv[0] = zf; kv[1] = zf; vv[0] = zf; vv[1] = zf;

  #pragma unroll
  for (int kt = 0; kt < 16; ++kt) {
    int k0 = kt * 16 + hf * 8;
    int kg = 2 * kt + hf;
    uint4 ux0 = ldsX[(kg * 64 + l31) ^ (kg >> 2)];
    uint4 ux1 = ldsX[(kg * 64 + 32 + l31) ^ (kg >> 2)];
    bf16x8 xf0 = frag_from_u4(ux0.x, ux0.y, ux0.z, ux0.w);
    bf16x8 xf1 = frag_from_u4(ux1.x, ux1.y, ux1.z, ux1.w);
    bf16x8 fq = *(const bf16x8*)(wq + k0);
    bf16x8 fk = *(const bf16x8*)(wk + k0);
    bf16x8 fv = *(const bf16x8*)(wv + k0);
    qt[0] = MFMA32(fq, xf0, qt[0]);  qt[1] = MFMA32(fq, xf1, qt[1]);
    kv[0] = MFMA32(fk, xf0, kv[0]);  kv[1] = MFMA32(fk, xf1, kv[1]);
    vv[0] = MFMA32(xf0, fv, vv[0]);  vv[1] = MFMA32(xf1, fv, vv[1]);
  }

  // ---- phase 2: S^T = K · Q^T  (s[ai][bi]: row n = key tok, col m = query tok)
  f32x16 s[2][2];
  s[0][0] = zf; s[0][1] = zf; s[1][0] = zf; s[1][1] = zf;
  #pragma unroll
  for (int kt = 0; kt < 2; ++kt) {
    bf16x8 aK0 = makefrag(kv[0], kt, hf);
    bf16x8 aK1 = makefrag(kv[1], kt, hf);
    bf16x8 bQ0 = makefrag(qt[0], kt, hf);
    bf16x8 bQ1 = makefrag(qt[1], kt, hf);
    s[0][0] = MFMA32(aK0, bQ0, s[0][0]);
    s[0][1] = MFMA32(aK0, bQ1, s[0][1]);
    s[1][0] = MFMA32(aK1, bQ0, s[1][0]);
    s[1][1] = MFMA32(aK1, bQ1, s[1][1]);
  }

  // ---- bias + shifted-window mask (dots[m][n], here at S^T element (n,m))
  const int maskUL = (wy == 15);
  const int maskLR = (wx == 15);
  #pragma unroll
  for (int ai = 0; ai < 2; ++ai)
    #pragma unroll
    for (int bi = 0; bi < 2; ++bi)
      #pragma unroll
      for (int r = 0; r < 16; ++r) {
        int n = (r & 3) + 8 * (r >> 2) + 4 * hf + 32 * ai;   // key token
        int m = l31 + 32 * bi;                               // query token
        float v = s[ai][bi][r] +
                  pos[((n >> 3) - (m >> 3) + 7) * 15 + ((n & 7) - (m & 7) + 7)];
        if ((maskUL && ((m >= 32) != (n >= 32))) ||
            (maskLR && (((m & 7) >= 4) != ((n & 7) >= 4))))
          v = -1e30f;
        s[ai][bi][r] = v;
      }

  // ---- softmax over n (rows of S^T): local reduce + one shfl_xor(32)
  #pragma unroll
  for (int bi = 0; bi < 2; ++bi) {
    float mx = -3e38f;
    #pragma unroll
    for (int ai = 0; ai < 2; ++ai)
      #pragma unroll
      for (int r = 0; r < 16; ++r) mx = fmaxf(mx, s[ai][bi][r]);
    mx = fmaxf(mx, __shfl_xor(mx, 32, 64));
    float sum = 0.0f;
    #pragma unroll
    for (int ai = 0; ai < 2; ++ai)
      #pragma unroll
      for (int r = 0; r < 16; ++r) {
        float p = exp2f((s[ai][bi][r] - mx) * LOG2E);
        s[ai][bi][r] = p;
        sum += p;
      }
    sum += __shfl_xor(sum, 32, 64);
    float ri = 1.0f / sum;
    #pragma unroll
    for (int ai = 0; ai < 2; ++ai)
      #pragma unroll
      for (int r = 0; r < 16; ++r) s[ai][bi][r] *= ri;
  }

  // ---- phase 3: O^T = V^T · P^T  (ot[bi]: row=d, col=query token) ------
  // A = makefrag(vv) -> A[m=d][k=key j];  B = makefrag(s) -> B[k=j][n=query].
  f32x16 ot[2];
  ot[0] = zf; ot[1] = zf;
  #pragma unroll
  for (int jt = 0; jt < 4; ++jt) {
    bf16x8 aV  = makefrag(vv[jt >> 1], jt & 1, hf);
    bf16x8 bP0 = makefrag(s[jt >> 1][0], jt & 1, hf);
    bf16x8 bP1 = makefrag(s[jt >> 1][1], jt & 1, hf);
    ot[0] = MFMA32(aV, bP0, ot[0]);
    ot[1] = MFMA32(aV, bP1, ot[1]);
  }

  // all waves must be done reading ldsX before ldsO overwrites the union
  __syncthreads();

  // ---- O^T -> LDS bf16 (k = h*32 + d, k-grouped slots, vector writes) --
  // lane owns col=token (bi*32+l31) and rows d = 8g + 4hf + (0..3) per
  // reg-quad g -> one 8B write per (bi,g): conflict-free contiguous 512B.
  {
    #pragma unroll
    for (int bi = 0; bi < 2; ++bi) {
      int tok = bi * 32 + l31;
      #pragma unroll
      for (int g = 0; g < 4; ++g) {
        int kg = h * 4 + g;                // (h*32 + d)>>3, d = 8g+...
        uint2 wv2;
        wv2.x = pack2(ot[bi][4 * g + 0], ot[bi][4 * g + 1]);
        wv2.y = pack2(ot[bi][4 * g + 2], ot[bi][4 * g + 3]);
        *(uint2*)&ldsO[(kg * 64 + tok) * 8 + 4 * hf] = wv2;
      }
    }
  }
  __syncthreads();

  // ---- phase 4: out^T = W_out^T · O^T  (wave h -> out cols h*32..h*32+31)
  const ushort* wo = WoT + (h * 32 + l31) * 256;
  f32x16 u[2];
  u[0] = zf; u[1] = zf;
  #pragma unroll
  for (int kt = 0; kt < 16; ++kt) {
    int k0 = kt * 16 + hf * 8;
    int kg = 2 * kt + hf;
    bf16x8 wa = *(const bf16x8*)(wo + k0);
    bf16x8 b0 = *(const bf16x8*)&ldsO[(kg * 64 + l31) * 8];
    bf16x8 b1 = *(const bf16x8*)&ldsO[(kg * 64 + 32 + l31) * 8];
    u[0] = MFMA32(wa, b0, u[0]);
    u[1] = MFMA32(wa, b1, u[1]);
  }

  // ---- epilogue: + b_out, write fp32 with roll(+4,+4) folded in --------
  #pragma unroll
  for (int tt = 0; tt < 2; ++tt) {
    int tok = 32 * tt + l31;
    int ty = tok >> 3, tx = tok & 7;
    int yy = (wy * 8 + ty + 4) & 127;
    int xx = (wx * 8 + tx + 4) & 127;
    float* ob = out + (((b * 128 + yy) * 128 + xx) << 8);
    #pragma unroll
    for (int g = 0; g < 4; ++g) {
      int c0 = h * 32 + 8 * g + 4 * hf;
      float4 bo = *(const float4*)(bout + c0);
      float4 v;
      v.x = (tt ? u[1][4 * g + 0] : u[0][4 * g + 0]) + bo.x;
      v.y = (tt ? u[1][4 * g + 1] : u[0][4 * g + 1]) + bo.y;
      v.z = (tt ? u[1][4 * g + 2] : u[0][4 * g + 2]) + bo.z;
      v.w = (tt ? u[1][4 * g + 3] : u[0][4 * g + 3]) + bo.w;
      *(float4*)(ob + c0) = v;
    }
  }
}

// ---------------------------------------------------------------------------
extern "C" void kernel_launch(void* const* d_in, const int* in_sizes, int n_in,
                              void* d_out, int out_size, void* d_ws, size_t ws_size,
                              hipStream_t stream) {
  const float* x    = (const float*)d_in[0];
  const float* wqkv = (const float*)d_in[1];
  const float* pos  = (const float*)d_in[2];
  const float* wout = (const float*)d_in[3];
  const float* bout = (const float*)d_in[4];

  ushort* WT  = (ushort*)d_ws;       // [768][256] bf16
  ushort* WoT = WT + 768 * 256;      // [256][256] bf16

  prep_weights<<<1024, 256, 0, stream>>>(wqkv, wout, WT, WoT);
  swin_attn<<<2048, 512, 0, stream>>>(x, pos, bout, WT, WoT, (float*)d_out);
}

// Round 5
// 239.157 us; speedup vs baseline: 7.8314x; 7.8314x over previous
//
#include <hip/hip_runtime.h>
#include <hip/hip_bf16.h>

// ---------------------------------------------------------------------------
// Swin shifted-window attention, fully fused per-window kernel.
//   x:[8,128,128,256] f32, w_qkv:[256,768], pos:[15,15], w_out:[256,256], b_out:[256]
//   out:[8,128,128,256] f32
// One block = one (batch, wy, wx) window; 512 threads = 8 waves = 8 heads.
// All matmuls via v_mfma_f32_32x32x16_bf16, fp32 accumulate.
//
// Journal:
//  R1: fused kernel, 64KB LDS, shfl makefrag               -> PASS 231 us
//  R2: 32KB LDS union + vectorized O^T spill + bounds(512,6)-> PASS 1873 us
//      (launch_bounds arg2=6 capped VGPR at 40 -> 8.8 GB spill traffic;
//       the 32KB union + O^T direct-compute themselves are good)
//  R3: + permlane32_swap INLINE ASM makefrag, Btab C-init, early frag conv,
//      deferred 1/sum                                       -> FAIL NaN
//      (inline-asm permlane bypasses compiler hazard modeling -> garbage reg
//       reads; the other three changes have no NaN path)
//  R4: revert to PROVEN shfl_xor makefrag; keep 32KB union, bounds(512,2),
//      Btab C-init, early conversion, deferred 1/sum.
//      -> infra failure (UnresponsiveContainer), never ran. R5 = resubmit.
//
// MFMA 32x32x16 layouts (guide §3, m74/m101 verified; passed R1/R2):
//   A-frag: lane l supplies A[m = l%32][k = 8*(l>>5)+i], i=0..7 (8 bf16 = 16B)
//   B-frag: lane l supplies B[k = 8*(l>>5)+i][n = l%32]
//   C/D   : element (row,col): col = l&31, row = (reg&3) + 8*(reg>>2) + 4*(l>>5)
// ---------------------------------------------------------------------------

typedef __attribute__((ext_vector_type(8)))  short bf16x8;
typedef __attribute__((ext_vector_type(16))) float f32x16;

#define MFMA32(a, b, c) __builtin_amdgcn_mfma_f32_32x32x16_bf16((a), (b), (c), 0, 0, 0)

#define QK_SCALE 0.17677669529663687f  // 1/sqrt(32)
#define LOG2E    1.44269504088896340f

__device__ __forceinline__ uint32_t pack2(float lo, float hi) {
  uint32_t l = (uint32_t)__bfloat16_as_ushort(__float2bfloat16(lo));
  uint32_t h = (uint32_t)__bfloat16_as_ushort(__float2bfloat16(hi));
  return l | (h << 16);
}

__device__ __forceinline__ bf16x8 frag_from_u4(uint32_t a, uint32_t b,
                                               uint32_t c, uint32_t d) {
  union { uint32_t u[4]; bf16x8 v; } r;
  r.u[0] = a; r.u[1] = b; r.u[2] = c; r.u[3] = d;
  return r.v;
}

// Assemble an MFMA A/B fragment whose k-dim walks the ROW index of a 32x32
// accumulator (acc element: row=(reg&3)+8*(reg>>2)+4*hf, col=lane&31) and
// whose m/n index equals col.  Fragment k = 16*kt + 8*hf + i.
// Own lane holds rows with bit2(row)==hf; partner (lane^32, same col) holds
// the complement -> 4 packs + 4 shfl_xor(32) + 4 selects.  (PROVEN R1/R2;
// the permlane32_swap inline-asm variant NaN'd in R3 — do not reintroduce
// without the __builtin_amdgcn_permlane32_swap form.)
__device__ __forceinline__ bf16x8 makefrag(const f32x16& a, int kt, int hf) {
  const int b0 = kt * 8;
  uint32_t q0 = pack2(a[b0 + 0], a[b0 + 1]);
  uint32_t q1 = pack2(a[b0 + 2], a[b0 + 3]);
  uint32_t q2 = pack2(a[b0 + 4], a[b0 + 5]);
  uint32_t q3 = pack2(a[b0 + 6], a[b0 + 7]);
  uint32_t x0 = (uint32_t)__shfl_xor((int)q0, 32, 64);
  uint32_t x1 = (uint32_t)__shfl_xor((int)q1, 32, 64);
  uint32_t x2 = (uint32_t)__shfl_xor((int)q2, 32, 64);
  uint32_t x3 = (uint32_t)__shfl_xor((int)q3, 32, 64);
  uint32_t d0 = hf ? x2 : q0;
  uint32_t d1 = hf ? x3 : q1;
  uint32_t d2 = hf ? q2 : x0;
  uint32_t d3 = hf ? q3 : x1;
  return frag_from_u4(d0, d1, d2, d3);
}

// ---------------------------------------------------------------------------
// Prep: w_qkv [256][768] -> WT bf16 [768][256] (row n = output col, contig k),
//       q-section pre-scaled; w_out -> WoT bf16 transposed;
//       bias+mask table Btab[type][n][m] (type = UL*2+LR), S^T orientation.
// ---------------------------------------------------------------------------
__global__ void prep_weights(const float* __restrict__ wqkv,
                             const float* __restrict__ wout,
                             const float* __restrict__ pos,
                             ushort* __restrict__ WT,
                             ushort* __restrict__ WoT,
                             float* __restrict__ Btab) {
  int id = blockIdx.x * 256 + threadIdx.x;
  if (id < 196608) {                       // 768*256
    int n = id >> 8, k = id & 255;
    float v = wqkv[k * 768 + n];
    if (n < 256) v *= QK_SCALE;            // fold QK scale into Wq
    WT[id] = __bfloat16_as_ushort(__float2bfloat16(v));
  } else if (id < 262144) {                // + 256*256
    int j = id - 196608;
    int n = j >> 8, k = j & 255;
    WoT[j] = __bfloat16_as_ushort(__float2bfloat16(wout[k * 256 + n]));
  } else if (id < 278528) {                // + 4*64*64 bias/mask table
    int j = id - 262144;
    int type = j >> 12, n = (j >> 6) & 63, m = j & 63;
    float v = pos[((n >> 3) - (m >> 3) + 7) * 15 + ((n & 7) - (m & 7) + 7)];
    bool ul = (m >= 32) != (n >= 32);
    bool lr = ((m & 7) >= 4) != ((n & 7) >= 4);
    if (((type & 2) && ul) || ((type & 1) && lr)) v = -1e30f;
    Btab[j] = v;
  }
}

// ---------------------------------------------------------------------------
__global__ __launch_bounds__(512, 2) void swin_attn(
    const float* __restrict__ x, const float* __restrict__ bout,
    const ushort* __restrict__ WT, const ushort* __restrict__ WoT,
    const float* __restrict__ Btab, float* __restrict__ out) {
  // 32 KB union buffer:
  //  phase 0-1: x window bf16, k-grouped: slot(kg,tok) = 16B holding
  //             k=8kg..8kg+7 for token tok; swizzled slot ^= (kg>>2).
  //  phase 3-4: O^T bf16, same k-grouped slot layout (k = h*32+d), no swizzle.
  __shared__ uint4 lds[32 * 64];
  uint4*  ldsX = lds;
  ushort* ldsO = (ushort*)lds;

  const int bid = blockIdx.x;
  const int b  = bid >> 8;
  const int wy = (bid >> 4) & 15;
  const int wx = bid & 15;
  const int t    = threadIdx.x;
  const int lane = t & 63;
  const int h    = t >> 6;                 // wave id == head id
  const int l31  = lane & 31;
  const int hf   = lane >> 5;

  f32x16 zf;
  #pragma unroll
  for (int i = 0; i < 16; ++i) zf[i] = 0.0f;

  // ---- stage shifted x window -> LDS bf16 -------------------------------
  {
    int tok = t >> 3, kc = t & 7;
    int ty = tok >> 3, tx = tok & 7;
    int yy = (wy * 8 + ty + 4) & 127;      // roll(-4,-4) folded into read
    int xx = (wx * 8 + tx + 4) & 127;
    const float* xr = x + (((b * 128 + yy) * 128 + xx) << 8) + kc * 32;
    #pragma unroll
    for (int g = 0; g < 4; ++g) {
      float4 a = *(const float4*)(xr + g * 8);
      float4 c = *(const float4*)(xr + g * 8 + 4);
      uint4 w;
      w.x = pack2(a.x, a.y); w.y = pack2(a.z, a.w);
      w.z = pack2(c.x, c.y); w.w = pack2(c.z, c.w);
      int kg = kc * 4 + g;
      ldsX[(kg * 64 + tok) ^ kc] = w;      // kc == kg>>2
    }
  }
  __syncthreads();

  // ---- phase 1: QKV.  qt/kv accs hold Q^T,K^T (row=d, col=token);
  //      vv holds V (row=token, col=d). Same x-frag feeds all three.
  const ushort* wq = WT + (h * 32 + l31) * 256;
  const ushort* wk = wq + 65536;
  const ushort* wv = wk + 65536;
  f32x16 qt[2], kv[2], vv[2];
  qt[0] = zf; qt[1] = zf; kv[0] = zf; kv[1] = zf; vv[0] = zf; vv[1] = zf;

  #pragma unroll
  for (int kt = 0; kt < 16; ++kt) {
    int k0 = kt * 16 + hf * 8;
    int kg = 2 * kt + hf;
    uint4 ux0 = ldsX[(kg * 64 + l31) ^ (kg >> 2)];
    uint4 ux1 = ldsX[(kg * 64 + 32 + l31) ^ (kg >> 2)];
    bf16x8 xf0 = frag_from_u4(ux0.x, ux0.y, ux0.z, ux0.w);
    bf16x8 xf1 = frag_from_u4(ux1.x, ux1.y, ux1.z, ux1.w);
    bf16x8 fq = *(const bf16x8*)(wq + k0);
    bf16x8 fk = *(const bf16x8*)(wk + k0);
    bf16x8 fv = *(const bf16x8*)(wv + k0);
    qt[0] = MFMA32(fq, xf0, qt[0]);  qt[1] = MFMA32(fq, xf1, qt[1]);
    kv[0] = MFMA32(fk, xf0, kv[0]);  kv[1] = MFMA32(fk, xf1, kv[1]);
    vv[0] = MFMA32(xf0, fv, vv[0]);  vv[1] = MFMA32(xf1, fv, vv[1]);
  }

  // ---- convert Q^T/K^T/V to bf16 fragments (frees f32 accumulators) ----
  bf16x8 fK[2][2], fQ[2][2], fV[2][2];
  #pragma unroll
  for (int ai = 0; ai < 2; ++ai)
    #pragma unroll
    for (int kt = 0; kt < 2; ++kt) fK[ai][kt] = makefrag(kv[ai], kt, hf);
  #pragma unroll
  for (int bi = 0; bi < 2; ++bi)
    #pragma unroll
    for (int kt = 0; kt < 2; ++kt) fQ[bi][kt] = makefrag(qt[bi], kt, hf);
  #pragma unroll
  for (int ai = 0; ai < 2; ++ai)
    #pragma unroll
    for (int kt = 0; kt < 2; ++kt) fV[ai][kt] = makefrag(vv[ai], kt, hf);

  // ---- phase 2: S^T = K · Q^T, C-initialized with bias+mask table -------
  const float* Tb = Btab + ((((wy == 15) ? 2 : 0) | ((wx == 15) ? 1 : 0)) << 12);
  f32x16 s[2][2];
  #pragma unroll
  for (int ai = 0; ai < 2; ++ai)
    #pragma unroll
    for (int bi = 0; bi < 2; ++bi)
      #pragma unroll
      for (int r = 0; r < 16; ++r) {
        int n = (r & 3) + 8 * (r >> 2) + 4 * hf + 32 * ai;   // key token
        s[ai][bi][r] = Tb[n * 64 + l31 + 32 * bi];
      }
  #pragma unroll
  for (int kt = 0; kt < 2; ++kt) {
    s[0][0] = MFMA32(fK[0][kt], fQ[0][kt], s[0][0]);
    s[0][1] = MFMA32(fK[0][kt], fQ[1][kt], s[0][1]);
    s[1][0] = MFMA32(fK[1][kt], fQ[0][kt], s[1][0]);
    s[1][1] = MFMA32(fK[1][kt], fQ[1][kt], s[1][1]);
  }

  // ---- softmax over n (rows of S^T); 1/sum deferred to ot scale ---------
  float ri[2];
  #pragma unroll
  for (int bi = 0; bi < 2; ++bi) {
    float mx = -3e38f;
    #pragma unroll
    for (int ai = 0; ai < 2; ++ai)
      #pragma unroll
      for (int r = 0; r < 16; ++r) mx = fmaxf(mx, s[ai][bi][r]);
    mx = fmaxf(mx, __shfl_xor(mx, 32, 64));
    float sum = 0.0f;
    #pragma unroll
    for (int ai = 0; ai < 2; ++ai)
      #pragma unroll
      for (int r = 0; r < 16; ++r) {
        float p = exp2f((s[ai][bi][r] - mx) * LOG2E);
        s[ai][bi][r] = p;
        sum += p;
      }
    sum += __shfl_xor(sum, 32, 64);
    ri[bi] = 1.0f / sum;
  }

  // ---- phase 3: O^T = V^T · P^T  (ot[bi]: row=d, col=query token) ------
  f32x16 ot[2];
  ot[0] = zf; ot[1] = zf;
  #pragma unroll
  for (int jt = 0; jt < 4; ++jt) {
    bf16x8 aV  = fV[jt >> 1][jt & 1];
    bf16x8 bP0 = makefrag(s[jt >> 1][0], jt & 1, hf);
    bf16x8 bP1 = makefrag(s[jt >> 1][1], jt & 1, hf);
    ot[0] = MFMA32(aV, bP0, ot[0]);
    ot[1] = MFMA32(aV, bP1, ot[1]);
  }
  #pragma unroll
  for (int bi = 0; bi < 2; ++bi)
    #pragma unroll
    for (int r = 0; r < 16; ++r) ot[bi][r] *= ri[bi];

  // all waves must be done reading ldsX before ldsO overwrites the union
  __syncthreads();

  // ---- O^T -> LDS bf16 (k = h*32 + d, k-grouped slots, vector writes) --
  {
    #pragma unroll
    for (int bi = 0; bi < 2; ++bi) {
      int tok = bi * 32 + l31;
      #pragma unroll
      for (int g = 0; g < 4; ++g) {
        int kg = h * 4 + g;                // (h*32 + d)>>3, d = 8g+4hf+0..3
        uint2 wv2;
        wv2.x = pack2(ot[bi][4 * g + 0], ot[bi][4 * g + 1]);
        wv2.y = pack2(ot[bi][4 * g + 2], ot[bi][4 * g + 3]);
        *(uint2*)&ldsO[(kg * 64 + tok) * 8 + 4 * hf] = wv2;
      }
    }
  }
  __syncthreads();

  // ---- phase 4: out^T = W_out^T · O^T  (wave h -> out cols h*32..h*32+31)
  const ushort* wo = WoT + (h * 32 + l31) * 256;
  f32x16 u[2];
  u[0] = zf; u[1] = zf;
  #pragma unroll
  for (int kt = 0; kt < 16; ++kt) {
    int k0 = kt * 16 + hf * 8;
    int kg = 2 * kt + hf;
    bf16x8 wa = *(const bf16x8*)(wo + k0);
    bf16x8 b0 = *(const bf16x8*)&ldsO[(kg * 64 + l31) * 8];
    bf16x8 b1 = *(const bf16x8*)&ldsO[(kg * 64 + 32 + l31) * 8];
    u[0] = MFMA32(wa, b0, u[0]);
    u[1] = MFMA32(wa, b1, u[1]);
  }

  // ---- epilogue: + b_out, write fp32 with roll(+4,+4) folded in --------
  #pragma unroll
  for (int tt = 0; tt < 2; ++tt) {
    int tok = 32 * tt + l31;
    int ty = tok >> 3, tx = tok & 7;
    int yy = (wy * 8 + ty + 4) & 127;
    int xx = (wx * 8 + tx + 4) & 127;
    float* ob = out + (((b * 128 + yy) * 128 + xx) << 8);
    #pragma unroll
    for (int g = 0; g < 4; ++g) {
      int c0 = h * 32 + 8 * g + 4 * hf;
      float4 bo = *(const float4*)(bout + c0);
      float4 v;
      v.x = (tt ? u[1][4 * g + 0] : u[0][4 * g + 0]) + bo.x;
      v.y = (tt ? u[1][4 * g + 1] : u[0][4 * g + 1]) + bo.y;
      v.z = (tt ? u[1][4 * g + 2] : u[0][4 * g + 2]) + bo.z;
      v.w = (tt ? u[1][4 * g + 3] : u[0][4 * g + 3]) + bo.w;
      *(float4*)(ob + c0) = v;
    }
  }
}

// ---------------------------------------------------------------------------
extern "C" void kernel_launch(void* const* d_in, const int* in_sizes, int n_in,
                              void* d_out, int out_size, void* d_ws, size_t ws_size,
                              hipStream_t stream) {
  const float* x    = (const float*)d_in[0];
  const float* wqkv = (const float*)d_in[1];
  const float* pos  = (const float*)d_in[2];
  const float* wout = (const float*)d_in[3];
  const float* bout = (const float*)d_in[4];

  ushort* WT   = (ushort*)d_ws;                       // [768][256] bf16
  ushort* WoT  = WT + 768 * 256;                      // [256][256] bf16
  float*  Btab = (float*)((char*)d_ws + 524288);      // [4][64][64] f32

  prep_weights<<<1088, 256, 0, stream>>>(wqkv, wout, pos, WT, WoT, Btab);
  swin_attn<<<2048, 512, 0, stream>>>(x, bout, WT, WoT, Btab, (float*)d_out);
}

// Round 7
// 225.328 us; speedup vs baseline: 8.3120x; 1.0614x over previous
//
#include <hip/hip_runtime.h>
#include <hip/hip_bf16.h>

// ---------------------------------------------------------------------------
// Swin shifted-window attention, fully fused per-window kernel.
//   x:[8,128,128,256] f32, w_qkv:[256,768], pos:[15,15], w_out:[256,256], b_out:[256]
//   out:[8,128,128,256] f32
// One block = one (batch, wy, wx) window; 512 threads = 8 waves = 8 heads.
// All matmuls via v_mfma_f32_32x32x16_bf16, fp32 accumulate.
//
// Journal:
//  R1: fused kernel, 64KB LDS, shfl makefrag                -> PASS 231 us
//  R2: 32KB union + vectorized O^T spill + bounds(512,6)    -> PASS 1873 us
//      (arg2 is BLOCKS/CU here: 6 -> 40-reg cap -> 8.8 GB spill traffic)
//  R3: + permlane32_swap INLINE ASM makefrag, Btab C-init,
//      early frag conv, deferred 1/sum                      -> FAIL NaN
//  R4: (= R5 source) infra failure, never ran
//  R5: revert to shfl makefrag, keep Btab/early-conv/defer  -> PASS 239 us
//      absmax 9.8e-4; permlane-asm convicted as the NaN source.
//      Occupancy still 23% ~= 1 block/CU: 96 f32 acc (qt/kv/vv) in AGPR +
//      100 VGPR ~= 196 total regs -> 2 waves/SIMD.
//  R6: sequential Q->K->V accumulation reusing ONE f32x16 pair (32 regs),
//      each converted to bf16 frags when done; order Q,K,S,V,softmax,PV.
//      ldsX read 3x (cheap). Target: <=128 total regs -> 2 blocks/CU.
//      -> infra failure (UnresponsiveContainer), never ran. R7 = resubmit.
//
// MFMA 32x32x16 layouts (guide §3, m74/m101 verified; passed R1/R2/R5):
//   A-frag: lane l supplies A[m = l%32][k = 8*(l>>5)+i], i=0..7 (8 bf16 = 16B)
//   B-frag: lane l supplies B[k = 8*(l>>5)+i][n = l%32]
//   C/D   : element (row,col): col = l&31, row = (reg&3) + 8*(reg>>2) + 4*(l>>5)
// ---------------------------------------------------------------------------

typedef __attribute__((ext_vector_type(8)))  short bf16x8;
typedef __attribute__((ext_vector_type(16))) float f32x16;

#define MFMA32(a, b, c) __builtin_amdgcn_mfma_f32_32x32x16_bf16((a), (b), (c), 0, 0, 0)

#define QK_SCALE 0.17677669529663687f  // 1/sqrt(32)
#define LOG2E    1.44269504088896340f

__device__ __forceinline__ uint32_t pack2(float lo, float hi) {
  uint32_t l = (uint32_t)__bfloat16_as_ushort(__float2bfloat16(lo));
  uint32_t h = (uint32_t)__bfloat16_as_ushort(__float2bfloat16(hi));
  return l | (h << 16);
}

__device__ __forceinline__ bf16x8 frag_from_u4(uint32_t a, uint32_t b,
                                               uint32_t c, uint32_t d) {
  union { uint32_t u[4]; bf16x8 v; } r;
  r.u[0] = a; r.u[1] = b; r.u[2] = c; r.u[3] = d;
  return r.v;
}

// Assemble an MFMA A/B fragment whose k-dim walks the ROW index of a 32x32
// accumulator (acc element: row=(reg&3)+8*(reg>>2)+4*hf, col=lane&31) and
// whose m/n index equals col.  Fragment k = 16*kt + 8*hf + i.
// Own lane holds rows with bit2(row)==hf; partner (lane^32, same col) holds
// the complement -> 4 packs + 4 shfl_xor(32) + 4 selects.  (PROVEN R1/R2/R5;
// the permlane32_swap inline-asm variant NaN'd in R3 — do not reintroduce
// without the __builtin_amdgcn_permlane32_swap form.)
__device__ __forceinline__ bf16x8 makefrag(const f32x16& a, int kt, int hf) {
  const int b0 = kt * 8;
  uint32_t q0 = pack2(a[b0 + 0], a[b0 + 1]);
  uint32_t q1 = pack2(a[b0 + 2], a[b0 + 3]);
  uint32_t q2 = pack2(a[b0 + 4], a[b0 + 5]);
  uint32_t q3 = pack2(a[b0 + 6], a[b0 + 7]);
  uint32_t x0 = (uint32_t)__shfl_xor((int)q0, 32, 64);
  uint32_t x1 = (uint32_t)__shfl_xor((int)q1, 32, 64);
  uint32_t x2 = (uint32_t)__shfl_xor((int)q2, 32, 64);
  uint32_t x3 = (uint32_t)__shfl_xor((int)q3, 32, 64);
  uint32_t d0 = hf ? x2 : q0;
  uint32_t d1 = hf ? x3 : q1;
  uint32_t d2 = hf ? q2 : x0;
  uint32_t d3 = hf ? q3 : x1;
  return frag_from_u4(d0, d1, d2, d3);
}

// ---------------------------------------------------------------------------
// Prep: w_qkv [256][768] -> WT bf16 [768][256] (row n = output col, contig k),
//       q-section pre-scaled; w_out -> WoT bf16 transposed;
//       bias+mask table Btab[type][n][m] (type = UL*2+LR), S^T orientation.
// ---------------------------------------------------------------------------
__global__ void prep_weights(const float* __restrict__ wqkv,
                             const float* __restrict__ wout,
                             const float* __restrict__ pos,
                             ushort* __restrict__ WT,
                             ushort* __restrict__ WoT,
                             float* __restrict__ Btab) {
  int id = blockIdx.x * 256 + threadIdx.x;
  if (id < 196608) {                       // 768*256
    int n = id >> 8, k = id & 255;
    float v = wqkv[k * 768 + n];
    if (n < 256) v *= QK_SCALE;            // fold QK scale into Wq
    WT[id] = __bfloat16_as_ushort(__float2bfloat16(v));
  } else if (id < 262144) {                // + 256*256
    int j = id - 196608;
    int n = j >> 8, k = j & 255;
    WoT[j] = __bfloat16_as_ushort(__float2bfloat16(wout[k * 256 + n]));
  } else if (id < 278528) {                // + 4*64*64 bias/mask table
    int j = id - 262144;
    int type = j >> 12, n = (j >> 6) & 63, m = j & 63;
    float v = pos[((n >> 3) - (m >> 3) + 7) * 15 + ((n & 7) - (m & 7) + 7)];
    bool ul = (m >= 32) != (n >= 32);
    bool lr = ((m & 7) >= 4) != ((n & 7) >= 4);
    if (((type & 2) && ul) || ((type & 1) && lr)) v = -1e30f;
    Btab[j] = v;
  }
}

// ---------------------------------------------------------------------------
__global__ __launch_bounds__(512, 2) void swin_attn(
    const float* __restrict__ x, const float* __restrict__ bout,
    const ushort* __restrict__ WT, const ushort* __restrict__ WoT,
    const float* __restrict__ Btab, float* __restrict__ out) {
  // 32 KB union buffer:
  //  phase 0-2: x window bf16, k-grouped: slot(kg,tok) = 16B holding
  //             k=8kg..8kg+7 for token tok; swizzled slot ^= (kg>>2).
  //  phase 3-4: O^T bf16, same k-grouped slot layout (k = h*32+d), no swizzle.
  __shared__ uint4 lds[32 * 64];
  uint4*  ldsX = lds;
  ushort* ldsO = (ushort*)lds;

  const int bid = blockIdx.x;
  const int b  = bid >> 8;
  const int wy = (bid >> 4) & 15;
  const int wx = bid & 15;
  const int t    = threadIdx.x;
  const int lane = t & 63;
  const int h    = t >> 6;                 // wave id == head id
  const int l31  = lane & 31;
  const int hf   = lane >> 5;

  f32x16 zf;
  #pragma unroll
  for (int i = 0; i < 16; ++i) zf[i] = 0.0f;

  // ---- stage shifted x window -> LDS bf16 -------------------------------
  {
    int tok = t >> 3, kc = t & 7;
    int ty = tok >> 3, tx = tok & 7;
    int yy = (wy * 8 + ty + 4) & 127;      // roll(-4,-4) folded into read
    int xx = (wx * 8 + tx + 4) & 127;
    const float* xr = x + (((b * 128 + yy) * 128 + xx) << 8) + kc * 32;
    #pragma unroll
    for (int g = 0; g < 4; ++g) {
      float4 a = *(const float4*)(xr + g * 8);
      float4 c = *(const float4*)(xr + g * 8 + 4);
      uint4 w;
      w.x = pack2(a.x, a.y); w.y = pack2(a.z, a.w);
      w.z = pack2(c.x, c.y); w.w = pack2(c.z, c.w);
      int kg = kc * 4 + g;
      ldsX[(kg * 64 + tok) ^ kc] = w;      // kc == kg>>2
    }
  }
  __syncthreads();

  const ushort* wq = WT + (h * 32 + l31) * 256;
  const ushort* wk = wq + 65536;
  const ushort* wv = wk + 65536;

  // Sequential projection passes sharing ONE accumulator pair (32 f32 regs
  // instead of 96): acc rows = output col (d), cols = token for Q/K;
  // rows = token, cols = d for V.
  f32x16 a0, a1;

  // ---- pass Q: Q^T = Wq · X^T -------------------------------------------
  a0 = zf; a1 = zf;
  #pragma unroll
  for (int kt = 0; kt < 16; ++kt) {
    int k0 = kt * 16 + hf * 8;
    int kg = 2 * kt + hf;
    uint4 ux0 = ldsX[(kg * 64 + l31) ^ (kg >> 2)];
    uint4 ux1 = ldsX[(kg * 64 + 32 + l31) ^ (kg >> 2)];
    bf16x8 xf0 = frag_from_u4(ux0.x, ux0.y, ux0.z, ux0.w);
    bf16x8 xf1 = frag_from_u4(ux1.x, ux1.y, ux1.z, ux1.w);
    bf16x8 fw = *(const bf16x8*)(wq + k0);
    a0 = MFMA32(fw, xf0, a0);  a1 = MFMA32(fw, xf1, a1);
  }
  bf16x8 fQ[2][2];
  #pragma unroll
  for (int kt = 0; kt < 2; ++kt) {
    fQ[0][kt] = makefrag(a0, kt, hf);
    fQ[1][kt] = makefrag(a1, kt, hf);
  }

  // ---- pass K: K^T = Wk · X^T -------------------------------------------
  a0 = zf; a1 = zf;
  #pragma unroll
  for (int kt = 0; kt < 16; ++kt) {
    int k0 = kt * 16 + hf * 8;
    int kg = 2 * kt + hf;
    uint4 ux0 = ldsX[(kg * 64 + l31) ^ (kg >> 2)];
    uint4 ux1 = ldsX[(kg * 64 + 32 + l31) ^ (kg >> 2)];
    bf16x8 xf0 = frag_from_u4(ux0.x, ux0.y, ux0.z, ux0.w);
    bf16x8 xf1 = frag_from_u4(ux1.x, ux1.y, ux1.z, ux1.w);
    bf16x8 fw = *(const bf16x8*)(wk + k0);
    a0 = MFMA32(fw, xf0, a0);  a1 = MFMA32(fw, xf1, a1);
  }
  bf16x8 fK[2][2];
  #pragma unroll
  for (int kt = 0; kt < 2; ++kt) {
    fK[0][kt] = makefrag(a0, kt, hf);
    fK[1][kt] = makefrag(a1, kt, hf);
  }

  // ---- S^T = K · Q^T, C-initialized with bias+mask table ----------------
  // (fQ/fK die after these 8 MFMAs, freeing 32 regs before the V pass)
  const float* Tb = Btab + ((((wy == 15) ? 2 : 0) | ((wx == 15) ? 1 : 0)) << 12);
  f32x16 s[2][2];
  #pragma unroll
  for (int ai = 0; ai < 2; ++ai)
    #pragma unroll
    for (int bi = 0; bi < 2; ++bi)
      #pragma unroll
      for (int r = 0; r < 16; ++r) {
        int n = (r & 3) + 8 * (r >> 2) + 4 * hf + 32 * ai;   // key token
        s[ai][bi][r] = Tb[n * 64 + l31 + 32 * bi];
      }
  #pragma unroll
  for (int kt = 0; kt < 2; ++kt) {
    s[0][0] = MFMA32(fK[0][kt], fQ[0][kt], s[0][0]);
    s[0][1] = MFMA32(fK[0][kt], fQ[1][kt], s[0][1]);
    s[1][0] = MFMA32(fK[1][kt], fQ[0][kt], s[1][0]);
    s[1][1] = MFMA32(fK[1][kt], fQ[1][kt], s[1][1]);
  }

  // ---- pass V: V = X · Wv  (rows = token, cols = d) ---------------------
  a0 = zf; a1 = zf;
  #pragma unroll
  for (int kt = 0; kt < 16; ++kt) {
    int k0 = kt * 16 + hf * 8;
    int kg = 2 * kt + hf;
    uint4 ux0 = ldsX[(kg * 64 + l31) ^ (kg >> 2)];
    uint4 ux1 = ldsX[(kg * 64 + 32 + l31) ^ (kg >> 2)];
    bf16x8 xf0 = frag_from_u4(ux0.x, ux0.y, ux0.z, ux0.w);
    bf16x8 xf1 = frag_from_u4(ux1.x, ux1.y, ux1.z, ux1.w);
    bf16x8 fw = *(const bf16x8*)(wv + k0);
    a0 = MFMA32(xf0, fw, a0);  a1 = MFMA32(xf1, fw, a1);
  }
  bf16x8 fV[2][2];
  #pragma unroll
  for (int kt = 0; kt < 2; ++kt) {
    fV[0][kt] = makefrag(a0, kt, hf);
    fV[1][kt] = makefrag(a1, kt, hf);
  }

  // ---- softmax over n (rows of S^T); 1/sum deferred to ot scale ---------
  float ri[2];
  #pragma unroll
  for (int bi = 0; bi < 2; ++bi) {
    float mx = -3e38f;
    #pragma unroll
    for (int ai = 0; ai < 2; ++ai)
      #pragma unroll
      for (int r = 0; r < 16; ++r) mx = fmaxf(mx, s[ai][bi][r]);
    mx = fmaxf(mx, __shfl_xor(mx, 32, 64));
    float sum = 0.0f;
    #pragma unroll
    for (int ai = 0; ai < 2; ++ai)
      #pragma unroll
      for (int r = 0; r < 16; ++r) {
        float p = exp2f((s[ai][bi][r] - mx) * LOG2E);
        s[ai][bi][r] = p;
        sum += p;
      }
    sum += __shfl_xor(sum, 32, 64);
    ri[bi] = 1.0f / sum;
  }

  // ---- O^T = V^T · P^T  (ot[bi]: row=d, col=query token) ----------------
  f32x16 ot[2];
  ot[0] = zf; ot[1] = zf;
  #pragma unroll
  for (int jt = 0; jt < 4; ++jt) {
    bf16x8 aV  = fV[jt >> 1][jt & 1];
    bf16x8 bP0 = makefrag(s[jt >> 1][0], jt & 1, hf);
    bf16x8 bP1 = makefrag(s[jt >> 1][1], jt & 1, hf);
    ot[0] = MFMA32(aV, bP0, ot[0]);
    ot[1] = MFMA32(aV, bP1, ot[1]);
  }
  #pragma unroll
  for (int bi = 0; bi < 2; ++bi)
    #pragma unroll
    for (int r = 0; r < 16; ++r) ot[bi][r] *= ri[bi];

  // all waves must be done reading ldsX before ldsO overwrites the union
  __syncthreads();

  // ---- O^T -> LDS bf16 (k = h*32 + d, k-grouped slots, vector writes) --
  {
    #pragma unroll
    for (int bi = 0; bi < 2; ++bi) {
      int tok = bi * 32 + l31;
      #pragma unroll
      for (int g = 0; g < 4; ++g) {
        int kg = h * 4 + g;                // (h*32 + d)>>3, d = 8g+4hf+0..3
        uint2 wv2;
        wv2.x = pack2(ot[bi][4 * g + 0], ot[bi][4 * g + 1]);
        wv2.y = pack2(ot[bi][4 * g + 2], ot[bi][4 * g + 3]);
        *(uint2*)&ldsO[(kg * 64 + tok) * 8 + 4 * hf] = wv2;
      }
    }
  }
  __syncthreads();

  // ---- out-proj: out^T = W_out^T · O^T  (wave h -> out cols h*32..h*32+31)
  const ushort* wo = WoT + (h * 32 + l31) * 256;
  f32x16 u[2];
  u[0] = zf; u[1] = zf;
  #pragma unroll
  for (int kt = 0; kt < 16; ++kt) {
    int k0 = kt * 16 + hf * 8;
    int kg = 2 * kt + hf;
    bf16x8 wa = *(const bf16x8*)(wo + k0);
    bf16x8 b0 = *(const bf16x8*)&ldsO[(kg * 64 + l31) * 8];
    bf16x8 b1 = *(const bf16x8*)&ldsO[(kg * 64 + 32 + l31) * 8];
    u[0] = MFMA32(wa, b0, u[0]);
    u[1] = MFMA32(wa, b1, u[1]);
  }

  // ---- epilogue: + b_out, write fp32 with roll(+4,+4) folded in --------
  #pragma unroll
  for (int tt = 0; tt < 2; ++tt) {
    int tok = 32 * tt + l31;
    int ty = tok >> 3, tx = tok & 7;
    int yy = (wy * 8 + ty + 4) & 127;
    int xx = (wx * 8 + tx + 4) & 127;
    float* ob = out + (((b * 128 + yy) * 128 + xx) << 8);
    #pragma unroll
    for (int g = 0; g < 4; ++g) {
      int c0 = h * 32 + 8 * g + 4 * hf;
      float4 bo = *(const float4*)(bout + c0);
      float4 v;
      v.x = (tt ? u[1][4 * g + 0] : u[0][4 * g + 0]) + bo.x;
      v.y = (tt ? u[1][4 * g + 1] : u[0][4 * g + 1]) + bo.y;
      v.z = (tt ? u[1][4 * g + 2] : u[0][4 * g + 2]) + bo.z;
      v.w = (tt ? u[1][4 * g + 3] : u[0][4 * g + 3]) + bo.w;
      *(float4*)(ob + c0) = v;
    }
  }
}

// ---------------------------------------------------------------------------
extern "C" void kernel_launch(void* const* d_in, const int* in_sizes, int n_in,
                              void* d_out, int out_size, void* d_ws, size_t ws_size,
                              hipStream_t stream) {
  const float* x    = (const float*)d_in[0];
  const float* wqkv = (const float*)d_in[1];
  const float* pos  = (const float*)d_in[2];
  const float* wout = (const float*)d_in[3];
  const float* bout = (const float*)d_in[4];

  ushort* WT   = (ushort*)d_ws;                       // [768][256] bf16
  ushort* WoT  = WT + 768 * 256;                      // [256][256] bf16
  float*  Btab = (float*)((char*)d_ws + 524288);      // [4][64][64] f32

  prep_weights<<<1088, 256, 0, stream>>>(wqkv, wout, pos, WT, WoT, Btab);
  swin_attn<<<2048, 512, 0, stream>>>(x, bout, WT, WoT, Btab, (float*)d_out);
}

// Round 8
// 166.277 us; speedup vs baseline: 11.2639x; 1.3551x over previous
//
#include <hip/hip_runtime.h>
#include <hip/hip_bf16.h>

// ---------------------------------------------------------------------------
// Swin shifted-window attention, fully fused per-window kernel.
//   x:[8,128,128,256] f32, w_qkv:[256,768], pos:[15,15], w_out:[256,256], b_out:[256]
//   out:[8,128,128,256] f32
// One block = one (batch, wy, wx) window; 512 threads = 8 waves = 8 heads.
// All matmuls via v_mfma_f32_32x32x16_bf16, fp32 accumulate.
//
// Journal:
//  R1: fused kernel, 64KB LDS, shfl makefrag                -> PASS 231 us
//  R2: 32KB union + bounds(512,6)                            -> PASS 1873 us
//      (arg2 is BLOCKS/CU: 6 -> 40-reg cap -> 8.8 GB spill traffic)
//  R3: inline-asm permlane makefrag + Btab + early-conv      -> FAIL NaN
//  R5: shfl makefrag + Btab/early-conv/defer                 -> PASS 239 us
//  R7: sequential Q->K->V (one acc pair reused)              -> PASS 225 us
//      VGPR 100->128 (at cap; +33MB spill WRITE), occupancy no longer
//      binding. 28us/block ~= 67k cyc >> 1.2k cyc MFMA: latency-bound on
//      UNCOALESCED loads (weight frags lane-stride 512B = 32 lines/wave-load
//      x48; Btab 64 scattered 4B loads/lane).
//  R8: pre-pack weights+bias in FRAGMENT ORDER so every wave-load is a
//      contiguous 1KB burst: Wpack[sec][h][kt][lane][8bf16],
//      Bpack[type][ai][bi][rb][lane][4f32]. Same math, same reg structure.
//
// MFMA 32x32x16 layouts (guide §3, m74/m101 verified; passed R1/R2/R5/R7):
//   A-frag: lane l supplies A[m = l%32][k = 8*(l>>5)+i], i=0..7 (8 bf16 = 16B)
//   B-frag: lane l supplies B[k = 8*(l>>5)+i][n = l%32]
//   C/D   : element (row,col): col = l&31, row = (reg&3) + 8*(reg>>2) + 4*(l>>5)
// ---------------------------------------------------------------------------

typedef __attribute__((ext_vector_type(8)))  short bf16x8;
typedef __attribute__((ext_vector_type(16))) float f32x16;

#define MFMA32(a, b, c) __builtin_amdgcn_mfma_f32_32x32x16_bf16((a), (b), (c), 0, 0, 0)

#define QK_SCALE 0.17677669529663687f  // 1/sqrt(32)
#define LOG2E    1.44269504088896340f

__device__ __forceinline__ uint32_t pack2(float lo, float hi) {
  uint32_t l = (uint32_t)__bfloat16_as_ushort(__float2bfloat16(lo));
  uint32_t h = (uint32_t)__bfloat16_as_ushort(__float2bfloat16(hi));
  return l | (h << 16);
}

__device__ __forceinline__ bf16x8 frag_from_u4(uint32_t a, uint32_t b,
                                               uint32_t c, uint32_t d) {
  union { uint32_t u[4]; bf16x8 v; } r;
  r.u[0] = a; r.u[1] = b; r.u[2] = c; r.u[3] = d;
  return r.v;
}

// Fragment re-pack from a 32x32 accumulator: k walks acc ROW index, m/n = col.
// PROVEN shfl_xor form (R1/R2/R5/R7); inline-asm permlane NaN'd in R3.
__device__ __forceinline__ bf16x8 makefrag(const f32x16& a, int kt, int hf) {
  const int b0 = kt * 8;
  uint32_t q0 = pack2(a[b0 + 0], a[b0 + 1]);
  uint32_t q1 = pack2(a[b0 + 2], a[b0 + 3]);
  uint32_t q2 = pack2(a[b0 + 4], a[b0 + 5]);
  uint32_t q3 = pack2(a[b0 + 6], a[b0 + 7]);
  uint32_t x0 = (uint32_t)__shfl_xor((int)q0, 32, 64);
  uint32_t x1 = (uint32_t)__shfl_xor((int)q1, 32, 64);
  uint32_t x2 = (uint32_t)__shfl_xor((int)q2, 32, 64);
  uint32_t x3 = (uint32_t)__shfl_xor((int)q3, 32, 64);
  uint32_t d0 = hf ? x2 : q0;
  uint32_t d1 = hf ? x3 : q1;
  uint32_t d2 = hf ? q2 : x0;
  uint32_t d3 = hf ? q3 : x1;
  return frag_from_u4(d0, d1, d2, d3);
}

// ---------------------------------------------------------------------------
// Prep: emit FRAGMENT-ORDERED packs so main-kernel wave loads are contiguous.
//  Wpack  [sec(3: q,k,v)][h(8)][kt(16)][lane(64)][i(8)] bf16
//     value = wqkv[k*768 + sec*256 + n],  n = h*32+(lane&31),
//             k = kt*16 + (lane>>5)*8 + i;  q-section scaled by QK_SCALE.
//  WoPack [h][kt][lane][i] bf16 : value = wout[k*256 + n]
//  Bpack  [type(4)][ai(2)][bi(2)][rb(4)][lane(64)][j(4)] f32 : bias+mask at
//     S^T acc element r=rb*4+j: n = j + 8*rb + 4*(lane>>5) + 32*ai,
//     m = (lane&31) + 32*bi.
// ---------------------------------------------------------------------------
__global__ void prep_weights(const float* __restrict__ wqkv,
                             const float* __restrict__ wout,
                             const float* __restrict__ pos,
                             ushort* __restrict__ Wpack,
                             ushort* __restrict__ WoPack,
                             float* __restrict__ Bpack) {
  int id = blockIdx.x * 256 + threadIdx.x;
  if (id < 196608) {                       // 3*8*16*64*8
    int sec = id >> 16;
    int j = id & 65535;
    int h = j >> 13, kt = (j >> 9) & 15, lane = (j >> 3) & 63, i = j & 7;
    int n = h * 32 + (lane & 31);
    int k = kt * 16 + (lane >> 5) * 8 + i;
    float v = wqkv[k * 768 + sec * 256 + n];
    if (sec == 0) v *= QK_SCALE;
    Wpack[id] = __bfloat16_as_ushort(__float2bfloat16(v));
  } else if (id < 262144) {                // + 8*16*64*8
    int j = id - 196608;
    int h = j >> 13, kt = (j >> 9) & 15, lane = (j >> 3) & 63, i = j & 7;
    int n = h * 32 + (lane & 31);
    int k = kt * 16 + (lane >> 5) * 8 + i;
    WoPack[j] = __bfloat16_as_ushort(__float2bfloat16(wout[k * 256 + n]));
  } else if (id < 278528) {                // + 4*2*2*4*64*4
    int j = id - 262144;
    int type = j >> 12;
    int r12 = j & 4095;
    int ai = r12 >> 11, bi = (r12 >> 10) & 1, rb = (r12 >> 8) & 3;
    int lane = (r12 >> 2) & 63, jj = r12 & 3;
    int n = jj + 8 * rb + 4 * (lane >> 5) + 32 * ai;
    int m = (lane & 31) + 32 * bi;
    float v = pos[((n >> 3) - (m >> 3) + 7) * 15 + ((n & 7) - (m & 7) + 7)];
    bool ul = (m >= 32) != (n >= 32);
    bool lr = ((m & 7) >= 4) != ((n & 7) >= 4);
    if (((type & 2) && ul) || ((type & 1) && lr)) v = -1e30f;
    Bpack[j] = v;
  }
}

// ---------------------------------------------------------------------------
__global__ __launch_bounds__(512, 2) void swin_attn(
    const float* __restrict__ x, const float* __restrict__ bout,
    const ushort* __restrict__ Wpack, const ushort* __restrict__ WoPack,
    const float* __restrict__ Bpack, float* __restrict__ out) {
  // 32 KB union buffer:
  //  phase 0-2: x window bf16, k-grouped: slot(kg,tok) = 16B holding
  //             k=8kg..8kg+7 for token tok; swizzled slot ^= (kg>>2).
  //  phase 3-4: O^T bf16, same k-grouped slot layout (k = h*32+d), no swizzle.
  __shared__ uint4 lds[32 * 64];
  uint4*  ldsX = lds;
  ushort* ldsO = (ushort*)lds;

  const int bid = blockIdx.x;
  const int b  = bid >> 8;
  const int wy = (bid >> 4) & 15;
  const int wx = bid & 15;
  const int t    = threadIdx.x;
  const int lane = t & 63;
  const int h    = t >> 6;                 // wave id == head id
  const int l31  = lane & 31;
  const int hf   = lane >> 5;

  f32x16 zf;
  #pragma unroll
  for (int i = 0; i < 16; ++i) zf[i] = 0.0f;

  // ---- stage shifted x window -> LDS bf16 -------------------------------
  {
    int tok = t >> 3, kc = t & 7;
    int ty = tok >> 3, tx = tok & 7;
    int yy = (wy * 8 + ty + 4) & 127;      // roll(-4,-4) folded into read
    int xx = (wx * 8 + tx + 4) & 127;
    const float* xr = x + (((b * 128 + yy) * 128 + xx) << 8) + kc * 32;
    #pragma unroll
    for (int g = 0; g < 4; ++g) {
      float4 a = *(const float4*)(xr + g * 8);
      float4 c = *(const float4*)(xr + g * 8 + 4);
      uint4 w;
      w.x = pack2(a.x, a.y); w.y = pack2(a.z, a.w);
      w.z = pack2(c.x, c.y); w.w = pack2(c.z, c.w);
      int kg = kc * 4 + g;
      ldsX[(kg * 64 + tok) ^ kc] = w;      // kc == kg>>2
    }
  }
  __syncthreads();

  // Per-head fragment-ordered weight bases: wave-load at +kt*512 elems is a
  // contiguous 1KB burst (64 lanes x 16B).
  const ushort* wqp = Wpack + h * 8192;            // [kt][lane][8]
  const ushort* wkp = wqp + 65536;
  const ushort* wvp = wkp + 65536;

  // Sequential projection passes sharing ONE accumulator pair.
  f32x16 a0, a1;

  // ---- pass Q: Q^T = Wq · X^T -------------------------------------------
  a0 = zf; a1 = zf;
  #pragma unroll
  for (int kt = 0; kt < 16; ++kt) {
    int kg = 2 * kt + hf;
    uint4 ux0 = ldsX[(kg * 64 + l31) ^ (kg >> 2)];
    uint4 ux1 = ldsX[(kg * 64 + 32 + l31) ^ (kg >> 2)];
    bf16x8 xf0 = frag_from_u4(ux0.x, ux0.y, ux0.z, ux0.w);
    bf16x8 xf1 = frag_from_u4(ux1.x, ux1.y, ux1.z, ux1.w);
    bf16x8 fw = *(const bf16x8*)(wqp + kt * 512 + lane * 8);
    a0 = MFMA32(fw, xf0, a0);  a1 = MFMA32(fw, xf1, a1);
  }
  bf16x8 fQ[2][2];
  #pragma unroll
  for (int kt = 0; kt < 2; ++kt) {
    fQ[0][kt] = makefrag(a0, kt, hf);
    fQ[1][kt] = makefrag(a1, kt, hf);
  }

  // ---- pass K: K^T = Wk · X^T -------------------------------------------
  a0 = zf; a1 = zf;
  #pragma unroll
  for (int kt = 0; kt < 16; ++kt) {
    int kg = 2 * kt + hf;
    uint4 ux0 = ldsX[(kg * 64 + l31) ^ (kg >> 2)];
    uint4 ux1 = ldsX[(kg * 64 + 32 + l31) ^ (kg >> 2)];
    bf16x8 xf0 = frag_from_u4(ux0.x, ux0.y, ux0.z, ux0.w);
    bf16x8 xf1 = frag_from_u4(ux1.x, ux1.y, ux1.z, ux1.w);
    bf16x8 fw = *(const bf16x8*)(wkp + kt * 512 + lane * 8);
    a0 = MFMA32(fw, xf0, a0);  a1 = MFMA32(fw, xf1, a1);
  }
  bf16x8 fK[2][2];
  #pragma unroll
  for (int kt = 0; kt < 2; ++kt) {
    fK[0][kt] = makefrag(a0, kt, hf);
    fK[1][kt] = makefrag(a1, kt, hf);
  }

  // ---- S^T = K · Q^T, C-initialized with coalesced bias+mask loads ------
  const float* Bp = Bpack + ((((wy == 15) ? 2 : 0) | ((wx == 15) ? 1 : 0)) << 12);
  f32x16 s[2][2];
  #pragma unroll
  for (int ai = 0; ai < 2; ++ai)
    #pragma unroll
    for (int bi = 0; bi < 2; ++bi)
      #pragma unroll
      for (int rb = 0; rb < 4; ++rb) {
        float4 f4 = *(const float4*)(Bp + (((ai * 2 + bi) * 4 + rb) * 64 + lane) * 4);
        s[ai][bi][rb * 4 + 0] = f4.x;
        s[ai][bi][rb * 4 + 1] = f4.y;
        s[ai][bi][rb * 4 + 2] = f4.z;
        s[ai][bi][rb * 4 + 3] = f4.w;
      }
  #pragma unroll
  for (int kt = 0; kt < 2; ++kt) {
    s[0][0] = MFMA32(fK[0][kt], fQ[0][kt], s[0][0]);
    s[0][1] = MFMA32(fK[0][kt], fQ[1][kt], s[0][1]);
    s[1][0] = MFMA32(fK[1][kt], fQ[0][kt], s[1][0]);
    s[1][1] = MFMA32(fK[1][kt], fQ[1][kt], s[1][1]);
  }

  // ---- pass V: V = X · Wv  (rows = token, cols = d) ---------------------
  a0 = zf; a1 = zf;
  #pragma unroll
  for (int kt = 0; kt < 16; ++kt) {
    int kg = 2 * kt + hf;
    uint4 ux0 = ldsX[(kg * 64 + l31) ^ (kg >> 2)];
    uint4 ux1 = ldsX[(kg * 64 + 32 + l31) ^ (kg >> 2)];
    bf16x8 xf0 = frag_from_u4(ux0.x, ux0.y, ux0.z, ux0.w);
    bf16x8 xf1 = frag_from_u4(ux1.x, ux1.y, ux1.z, ux1.w);
    bf16x8 fw = *(const bf16x8*)(wvp + kt * 512 + lane * 8);
    a0 = MFMA32(xf0, fw, a0);  a1 = MFMA32(xf1, fw, a1);
  }
  bf16x8 fV[2][2];
  #pragma unroll
  for (int kt = 0; kt < 2; ++kt) {
    fV[0][kt] = makefrag(a0, kt, hf);
    fV[1][kt] = makefrag(a1, kt, hf);
  }

  // ---- softmax over n (rows of S^T); 1/sum deferred to ot scale ---------
  float ri[2];
  #pragma unroll
  for (int bi = 0; bi < 2; ++bi) {
    float mx = -3e38f;
    #pragma unroll
    for (int ai = 0; ai < 2; ++ai)
      #pragma unroll
      for (int r = 0; r < 16; ++r) mx = fmaxf(mx, s[ai][bi][r]);
    mx = fmaxf(mx, __shfl_xor(mx, 32, 64));
    float sum = 0.0f;
    #pragma unroll
    for (int ai = 0; ai < 2; ++ai)
      #pragma unroll
      for (int r = 0; r < 16; ++r) {
        float p = exp2f((s[ai][bi][r] - mx) * LOG2E);
        s[ai][bi][r] = p;
        sum += p;
      }
    sum += __shfl_xor(sum, 32, 64);
    ri[bi] = 1.0f / sum;
  }

  // ---- O^T = V^T · P^T  (ot[bi]: row=d, col=query token) ----------------
  f32x16 ot[2];
  ot[0] = zf; ot[1] = zf;
  #pragma unroll
  for (int jt = 0; jt < 4; ++jt) {
    bf16x8 aV  = fV[jt >> 1][jt & 1];
    bf16x8 bP0 = makefrag(s[jt >> 1][0], jt & 1, hf);
    bf16x8 bP1 = makefrag(s[jt >> 1][1], jt & 1, hf);
    ot[0] = MFMA32(aV, bP0, ot[0]);
    ot[1] = MFMA32(aV, bP1, ot[1]);
  }
  #pragma unroll
  for (int bi = 0; bi < 2; ++bi)
    #pragma unroll
    for (int r = 0; r < 16; ++r) ot[bi][r] *= ri[bi];

  // all waves must be done reading ldsX before ldsO overwrites the union
  __syncthreads();

  // ---- O^T -> LDS bf16 (k = h*32 + d, k-grouped slots, vector writes) --
  {
    #pragma unroll
    for (int bi = 0; bi < 2; ++bi) {
      int tok = bi * 32 + l31;
      #pragma unroll
      for (int g = 0; g < 4; ++g) {
        int kg = h * 4 + g;                // (h*32 + d)>>3, d = 8g+4hf+0..3
        uint2 wv2;
        wv2.x = pack2(ot[bi][4 * g + 0], ot[bi][4 * g + 1]);
        wv2.y = pack2(ot[bi][4 * g + 2], ot[bi][4 * g + 3]);
        *(uint2*)&ldsO[(kg * 64 + tok) * 8 + 4 * hf] = wv2;
      }
    }
  }
  __syncthreads();

  // ---- out-proj: out^T = W_out^T · O^T  (wave h -> out cols h*32..h*32+31)
  const ushort* wop = WoPack + h * 8192;
  f32x16 u[2];
  u[0] = zf; u[1] = zf;
  #pragma unroll
  for (int kt = 0; kt < 16; ++kt) {
    int kg = 2 * kt + hf;
    bf16x8 wa = *(const bf16x8*)(wop + kt * 512 + lane * 8);
    bf16x8 b0 = *(const bf16x8*)&ldsO[(kg * 64 + l31) * 8];
    bf16x8 b1 = *(const bf16x8*)&ldsO[(kg * 64 + 32 + l31) * 8];
    u[0] = MFMA32(wa, b0, u[0]);
    u[1] = MFMA32(wa, b1, u[1]);
  }

  // ---- epilogue: + b_out, write fp32 with roll(+4,+4) folded in --------
  #pragma unroll
  for (int tt = 0; tt < 2; ++tt) {
    int tok = 32 * tt + l31;
    int ty = tok >> 3, tx = tok & 7;
    int yy = (wy * 8 + ty + 4) & 127;
    int xx = (wx * 8 + tx + 4) & 127;
    float* ob = out + (((b * 128 + yy) * 128 + xx) << 8);
    #pragma unroll
    for (int g = 0; g < 4; ++g) {
      int c0 = h * 32 + 8 * g + 4 * hf;
      float4 bo = *(const float4*)(bout + c0);
      float4 v;
      v.x = (tt ? u[1][4 * g + 0] : u[0][4 * g + 0]) + bo.x;
      v.y = (tt ? u[1][4 * g + 1] : u[0][4 * g + 1]) + bo.y;
      v.z = (tt ? u[1][4 * g + 2] : u[0][4 * g + 2]) + bo.z;
      v.w = (tt ? u[1][4 * g + 3] : u[0][4 * g + 3]) + bo.w;
      *(float4*)(ob + c0) = v;
    }
  }
}

// ---------------------------------------------------------------------------
extern "C" void kernel_launch(void* const* d_in, const int* in_sizes, int n_in,
                              void* d_out, int out_size, void* d_ws, size_t ws_size,
                              hipStream_t stream) {
  const float* x    = (const float*)d_in[0];
  const float* wqkv = (const float*)d_in[1];
  const float* pos  = (const float*)d_in[2];
  const float* wout = (const float*)d_in[3];
  const float* bout = (const float*)d_in[4];

  ushort* Wpack  = (ushort*)d_ws;                     // [3][8][16][64][8] bf16
  ushort* WoPack = Wpack + 196608;                    // [8][16][64][8] bf16
  float*  Bpack  = (float*)((char*)d_ws + 524288);    // [4][2][2][4][64][4] f32

  prep_weights<<<1088, 256, 0, stream>>>(wqkv, wout, pos, Wpack, WoPack, Bpack);
  swin_attn<<<2048, 512, 0, stream>>>(x, bout, Wpack, WoPack, Bpack, (float*)d_out);
}